// Round 4
// baseline (443.121 us; speedup 1.0000x reference)
//
#include <hip/hip_runtime.h>

#define BB   8
#define CC   64
#define HH   128
#define WW   128
#define OCC  128
#define HWx  (HH*WW)
#define NOFF 18
#define KTOT 576
#define SST  584    // bf16 elems per pixel row in LDS: 576 + 8 pad
#define TILE 16
#define NT   8

typedef __attribute__((ext_vector_type(8))) short short8t;
typedef __attribute__((ext_vector_type(4))) float f32x4;

static __device__ __forceinline__ ushort f2bf(float f) {
    uint u = __float_as_uint(f);
    uint r = (u + 0x7fffu + ((u >> 16) & 1u)) >> 16;   // RNE
    return (ushort)r;
}

// ---------------- K0: conv_w fp32 -> bf16 (one-time per launch) -------------
__global__ __launch_bounds__(256) void kprep(const float* __restrict__ w,
                                             ushort* __restrict__ wb) {
    int i = blockIdx.x * 256 + threadIdx.x;   // 128*576 = 73728 total
    wb[i] = f2bf(w[i]);
}

// ---------------- K1: offset conv (channels 0..17 only), fp32 exact ---------
__global__ __launch_bounds__(256) void koff(const float* __restrict__ x,
                                            const float* __restrict__ off_w,
                                            const float* __restrict__ off_b,
                                            float* __restrict__ offs) {
    __shared__ float wl[576][20];
    int tid = threadIdx.x;
    for (int idx = tid; idx < 18 * 576; idx += 256) {
        int ch = idx / 576;
        int r  = idx % 576;
        wl[r][ch] = off_w[ch * 576 + r];
    }
    __syncthreads();

    int b  = blockIdx.x / (HH / 2);
    int i  = (blockIdx.x % (HH / 2)) * 2 + (tid >> 7);
    int j  = tid & 127;
    const float* xb = x + b * CC * HWx;

    float acc[18];
#pragma unroll
    for (int ch = 0; ch < 18; ++ch) acc[ch] = off_b[ch];

    for (int c = 0; c < CC; ++c) {
        const float* xc = xb + c * HWx;
#pragma unroll
        for (int di = 0; di < 3; ++di) {
            int r = i + di - 1;
            bool rv = (r >= 0) && (r < HH);
#pragma unroll
            for (int dj = 0; dj < 3; ++dj) {
                int s = j + dj - 1;
                float xv = (rv && s >= 0 && s < WW) ? xc[r * WW + s] : 0.f;
                const float* wrow = &wl[c * 9 + di * 3 + dj][0];
#pragma unroll
                for (int ch = 0; ch < 18; ++ch)
                    acc[ch] = fmaf(xv, wrow[ch], acc[ch]);
            }
        }
    }
    float* ob = offs + (b * NOFF) * HWx + i * WW + j;
#pragma unroll
    for (int ch = 0; ch < 18; ++ch) ob[ch * HWx] = acc[ch];
}

// ---------------- K2: producer/consumer fused sample + MFMA conv ------------
// Block = one output row (b, oi): 8 tiles of 16 pixels, S double-buffered.
// Waves 0-5 (384 thr): producers. Waves 6-7 (128 thr): consumers (GEMM).
__global__ __launch_bounds__(512, 6) void kmain4(const float* __restrict__ x,
                                                 const float* __restrict__ offs,
                                                 const ushort* __restrict__ wb,
                                                 const float* __restrict__ conv_b,
                                                 float* __restrict__ out) {
    __shared__ __align__(16) ushort S[2][TILE * SST];   // 2 x 18688 B
    int tid = threadIdx.x;
    int b   = blockIdx.x >> 7;
    int oi  = blockIdx.x & 127;
    const float* xb   = x + (size_t)b * CC * HWx;
    const float* offb = offs + (size_t)b * NOFF * HWx;

    if (tid < 384) {
        // ---------------- producers ----------------
        int pix = tid & 15;           // pixel within tile
        int cg  = (tid >> 4) & 7;     // channel group (8 ch each)
        int tg  = tid >> 7;           // 0..2 = tap column kc
        int sj_off = (tg == 0) ? -1 : 0;
        int k2  = (tg == 0) ? 2 : tg - 1;   // offset col index part

        for (int t = 0; t <= NT; ++t) {
            if (t < NT) {
                ushort* Sb = &S[t & 1][0];
                int oj = t * TILE + pix;
                int sj = oj + sj_off;
#pragma unroll
                for (int tt = 0; tt < 3; ++tt) {      // kr = tt
                    int tap = tg + tt * 3;
                    int si  = oi + ((tt == 0) ? -1 : 0);
                    if (si < 0 || sj < 0) {
#pragma unroll
                        for (int u = 0; u < 8; ++u)
                            Sb[pix * SST + (cg * 8 + u) * 9 + tap] = 0;
                        continue;
                    }
                    int n    = ((tt == 0) ? 2 : tt - 1) * 3 + k2;
                    int base = si * WW + sj;
                    float ox = offb[n * HWx + base];
                    float oy = offb[(n + 9) * HWx + base];
                    float px = (float)si + ox;
                    float py = (float)sj + oy;
                    float fx = floorf(px), fy = floorf(py);
                    float pxc   = fminf(fmaxf(px, 0.f), 127.f);
                    float pyc   = fminf(fmaxf(py, 0.f), 127.f);
                    float qltxf = fminf(fmaxf(fx, 0.f), 127.f);
                    float qltyf = fminf(fmaxf(fy, 0.f), 127.f);
                    float qrbxf = fminf(fmaxf(fx + 1.f, 0.f), 127.f);
                    float qrbyf = fminf(fmaxf(fy + 1.f, 0.f), 127.f);
                    int qltx = (int)qltxf, qlty = (int)qltyf;
                    int qrbx = (int)qrbxf, qrby = (int)qrbyf;
                    float glt = (1.f + (qltxf - pxc)) * (1.f + (qltyf - pyc));
                    float grb = (1.f - (qrbxf - pxc)) * (1.f - (qrbyf - pyc));
                    float glb = (1.f + (qltxf - pxc)) * (1.f - (qrbyf - pyc));
                    float grt = (1.f - (qrbxf - pxc)) * (1.f + (qltyf - pyc));
                    int alt = qltx * WW + qlty;
                    int arb = qrbx * WW + qrby;
                    int alb = qltx * WW + qrby;
                    int art = qrbx * WW + qlty;
#pragma unroll
                    for (int u = 0; u < 8; ++u) {
                        int c = cg * 8 + u;
                        const float* xc = xb + (size_t)c * HWx;
                        float v = glt * xc[alt] + grb * xc[arb]
                                + glb * xc[alb] + grt * xc[art];
                        Sb[pix * SST + c * 9 + tap] = f2bf(v);
                    }
                }
            }
            __syncthreads();
        }
    } else {
        // ---------------- consumers ----------------
        int ctid = tid - 384;
        int w2 = ctid >> 6;            // 0..1: oc half
        int l  = ctid & 63;
        int lr = l & 15;
        int lg = l >> 4;

        const ushort* wr[4];
        float bias[4][4];
#pragma unroll
        for (int a = 0; a < 4; ++a) {
            int ocb = w2 * 64 + a * 16;
            wr[a] = wb + (size_t)(ocb + lr) * KTOT + lg * 8;
#pragma unroll
            for (int e = 0; e < 4; ++e)
                bias[a][e] = conv_b[ocb + lg * 4 + e];
        }
        float* ob = out + (size_t)(b * OCC) * HWx + oi * WW;

        __syncthreads();               // matches producers' tile-0 barrier
        for (int t = 0; t < NT; ++t) {
            const ushort* sr = &S[t & 1][lr * SST + lg * 8];
            f32x4 acc[4];
#pragma unroll
            for (int a = 0; a < 4; ++a)
#pragma unroll
                for (int e = 0; e < 4; ++e) acc[a][e] = bias[a][e];

#pragma unroll 3
            for (int ks = 0; ks < 18; ++ks) {
                short8t bq = *(const short8t*)(sr + ks * 32);
                short8t a0 = *(const short8t*)(wr[0] + ks * 32);
                short8t a1 = *(const short8t*)(wr[1] + ks * 32);
                short8t a2 = *(const short8t*)(wr[2] + ks * 32);
                short8t a3 = *(const short8t*)(wr[3] + ks * 32);
                acc[0] = __builtin_amdgcn_mfma_f32_16x16x32_bf16(a0, bq, acc[0], 0, 0, 0);
                acc[1] = __builtin_amdgcn_mfma_f32_16x16x32_bf16(a1, bq, acc[1], 0, 0, 0);
                acc[2] = __builtin_amdgcn_mfma_f32_16x16x32_bf16(a2, bq, acc[2], 0, 0, 0);
                acc[3] = __builtin_amdgcn_mfma_f32_16x16x32_bf16(a3, bq, acc[3], 0, 0, 0);
            }
#pragma unroll
            for (int a = 0; a < 4; ++a) {
#pragma unroll
                for (int e = 0; e < 4; ++e) {
                    int oc = w2 * 64 + a * 16 + lg * 4 + e;
                    ob[(size_t)oc * HWx + t * TILE + lr] = acc[a][e];
                }
            }
            __syncthreads();
        }
    }
}

extern "C" void kernel_launch(void* const* d_in, const int* in_sizes, int n_in,
                              void* d_out, int out_size, void* d_ws, size_t ws_size,
                              hipStream_t stream) {
    const float* x      = (const float*)d_in[0];
    const float* off_w  = (const float*)d_in[1];
    const float* off_b  = (const float*)d_in[2];
    const float* conv_w = (const float*)d_in[3];
    const float* conv_b = (const float*)d_in[4];
    float* out  = (float*)d_out;

    ushort* wbf  = (ushort*)d_ws;                      // 147456 B
    float*  offs = (float*)((char*)d_ws + 147456);     // 9.44 MB

    kprep<<<(OCC * KTOT) / 256, 256, 0, stream>>>(conv_w, wbf);
    koff<<<BB * (HH / 2), 256, 0, stream>>>(x, off_w, off_b, offs);
    kmain4<<<BB * HH, 512, 0, stream>>>(x, offs, wbf, conv_b, out);
}

// Round 5
// 221.522 us; speedup vs baseline: 2.0003x; 2.0003x over previous
//
#include <hip/hip_runtime.h>

#define BB   8
#define CC   64
#define HH   128
#define WW   128
#define OCC  128
#define HWx  (HH*WW)
#define KTOT 576
#define SST  584    // ushort row stride: 576 + 8 (1168 B, 16B-multiple)

typedef __attribute__((ext_vector_type(8))) short short8t;
typedef __attribute__((ext_vector_type(4))) float f32x4;

static __device__ __forceinline__ ushort f2bf(float f) {
    uint u = __float_as_uint(f);
    uint r = (u + 0x7fffu + ((u >> 16) & 1u)) >> 16;   // RNE
    return (ushort)r;
}
static __device__ __forceinline__ float bf2f(ushort u) {
    return __uint_as_float(((uint)u) << 16);
}

// ---- K0: conv_w [oc][c*9+tap] fp32 -> wb [oc][tap*64+c] bf16 --------------
__global__ __launch_bounds__(256) void kprep(const float* __restrict__ w,
                                             ushort* __restrict__ wb) {
    int i = blockIdx.x * 256 + threadIdx.x;   // 73728
    int oc = i / KTOT, k = i - oc * KTOT;
    int c = k / 9, tap = k - c * 9;
    wb[oc * KTOT + tap * 64 + c] = f2bf(w[i]);
}

// ---- K0b: x NCHW fp32 -> xT NHWC bf16 -------------------------------------
__global__ __launch_bounds__(256) void ktrans(const float* __restrict__ x,
                                              ushort* __restrict__ xT) {
    __shared__ ushort st[256][72];            // 36864 B
    int tid = threadIdx.x;
    int b   = blockIdx.x >> 6;
    int p0  = (blockIdx.x & 63) * 256;
    const float* xb = x + (size_t)b * CC * HWx;
#pragma unroll 4
    for (int c = 0; c < 64; ++c)
        st[tid][c] = f2bf(xb[(size_t)c * HWx + p0 + tid]);
    __syncthreads();
    ushort* ob = xT + ((size_t)b * HWx + p0) * 64;
#pragma unroll
    for (int k = 0; k < 8; ++k) {
        int flat = k * 2048 + tid * 8;
        int p = flat >> 6, c = flat & 63;
        *(short8t*)(ob + (size_t)p * 64 + c) = *(const short8t*)&st[p][c];
    }
}

// ---- K1: offset conv (ch 0..17), fp32 exact, writes offsT[pix][18] --------
// grid BB*HH, 256 thr: g=tid>>7 handles 9 channels, j=tid&127.
__global__ __launch_bounds__(256) void koff(const float* __restrict__ x,
                                            const float* __restrict__ off_w,
                                            const float* __restrict__ off_b,
                                            float* __restrict__ offsT) {
    __shared__ float wl[576][20];
    int tid = threadIdx.x;
    for (int idx = tid; idx < 18 * 576; idx += 256) {
        int ch = idx / 576, r = idx - ch * 576;
        wl[r][ch] = off_w[ch * 576 + r];
    }
    __syncthreads();

    int b = blockIdx.x >> 7;
    int i = blockIdx.x & 127;
    int g = tid >> 7;            // channel group: ch = g*9 + u
    int j = tid & 127;
    const float* xb = x + (size_t)b * CC * HWx;

    float acc[9];
#pragma unroll
    for (int u = 0; u < 9; ++u) acc[u] = off_b[g * 9 + u];

    for (int c = 0; c < CC; ++c) {
        const float* xc = xb + (size_t)c * HWx;
#pragma unroll
        for (int di = 0; di < 3; ++di) {
            int r = i + di - 1;
            bool rv = (r >= 0) && (r < HH);
#pragma unroll
            for (int dj = 0; dj < 3; ++dj) {
                int s = j + dj - 1;
                float xv = (rv && s >= 0 && s < WW) ? xc[r * WW + s] : 0.f;
                const float* wrow = &wl[c * 9 + di * 3 + dj][g * 9];
#pragma unroll
                for (int u = 0; u < 9; ++u)
                    acc[u] = fmaf(xv, wrow[u], acc[u]);
            }
        }
    }
    float* ob = offsT + ((size_t)(b * HWx) + i * WW + j) * 18 + g * 9;
#pragma unroll
    for (int u = 0; u < 9; ++u) ob[u] = acc[u];
}

// ---- K2: fused vector-gather + MFMA stride-3 conv -------------------------
// Block: 256 thr, 32 pixels x 128 oc. grid = 8*128*4 = 4096.
__global__ __launch_bounds__(256) void kmain5(const ushort* __restrict__ xT,
                                              const float* __restrict__ offsT,
                                              const ushort* __restrict__ wb,
                                              const float* __restrict__ conv_b,
                                              float* __restrict__ out) {
    __shared__ __align__(16) ushort S[32 * SST];   // 37376 B
    int tid = threadIdx.x;
    int bi  = blockIdx.x;
    int b   = bi >> 9;
    int rem = bi & 511;
    int oi  = rem >> 2;
    int oj0 = (rem & 3) * 32;

    const ushort* xTb = xT + (size_t)b * HWx * 64;
    const float*  offb = offsT + (size_t)b * HWx * 18;

    // ---- phase 1: 576 subtasks = (pix, tap, half-of-channels) ----
    for (int s = tid; s < 576; s += 256) {
        int pix  = s / 18;
        int r    = s - pix * 18;
        int tap  = r >> 1;
        int half = r & 1;
        int kr = tap / 3, kc = tap - kr * 3;
        int si = oi + ((kr == 0) ? -1 : 0);
        int sj = oj0 + pix + ((kc == 0) ? -1 : 0);
        ushort* Sd = &S[pix * SST + tap * 64 + half * 32];

        if (si < 0 || sj < 0) {
            short8t z = {0, 0, 0, 0, 0, 0, 0, 0};
#pragma unroll
            for (int k = 0; k < 4; ++k) *(short8t*)(Sd + k * 8) = z;
            continue;
        }
        int n    = ((kr == 0) ? 2 : kr - 1) * 3 + ((kc == 0) ? 2 : kc - 1);
        int pidx = si * WW + sj;
        float ox = offb[pidx * 18 + n];
        float oy = offb[pidx * 18 + 9 + n];
        float px = (float)si + ox;
        float py = (float)sj + oy;
        float fx = floorf(px), fy = floorf(py);
        float pxc   = fminf(fmaxf(px, 0.f), 127.f);
        float pyc   = fminf(fmaxf(py, 0.f), 127.f);
        float qltxf = fminf(fmaxf(fx, 0.f), 127.f);
        float qltyf = fminf(fmaxf(fy, 0.f), 127.f);
        float qrbxf = fminf(fmaxf(fx + 1.f, 0.f), 127.f);
        float qrbyf = fminf(fmaxf(fy + 1.f, 0.f), 127.f);
        int qltx = (int)qltxf, qlty = (int)qltyf;
        int qrbx = (int)qrbxf, qrby = (int)qrbyf;
        float glt = (1.f + (qltxf - pxc)) * (1.f + (qltyf - pyc));
        float grb = (1.f - (qrbxf - pxc)) * (1.f - (qrbyf - pyc));
        float glb = (1.f + (qltxf - pxc)) * (1.f - (qrbyf - pyc));
        float grt = (1.f - (qrbxf - pxc)) * (1.f + (qltyf - pyc));
        int co = half * 32;
        const ushort* plt = xTb + (size_t)(qltx * WW + qlty) * 64 + co;
        const ushort* prb = xTb + (size_t)(qrbx * WW + qrby) * 64 + co;
        const ushort* plb = xTb + (size_t)(qltx * WW + qrby) * 64 + co;
        const ushort* prt = xTb + (size_t)(qrbx * WW + qlty) * 64 + co;
#pragma unroll
        for (int k = 0; k < 4; ++k) {
            short8t lt = *(const short8t*)(plt + k * 8);
            short8t rb = *(const short8t*)(prb + k * 8);
            short8t lb = *(const short8t*)(plb + k * 8);
            short8t rt = *(const short8t*)(prt + k * 8);
            short8t o;
#pragma unroll
            for (int e = 0; e < 8; ++e) {
                float v = glt * bf2f((ushort)lt[e]) + grb * bf2f((ushort)rb[e])
                        + glb * bf2f((ushort)lb[e]) + grt * bf2f((ushort)rt[e]);
                o[e] = (short)f2bf(v);
            }
            *(short8t*)(Sd + k * 8) = o;
        }
    }
    __syncthreads();

    // ---- phase 2: 128oc x 32pix x 576K GEMM (16x16x32 bf16 MFMA) ----
    int wv = tid >> 6;
    int l  = tid & 63;
    int lr = l & 15;
    int lg = l >> 4;

    f32x4 acc[2][2];
#pragma unroll
    for (int a = 0; a < 2; ++a) {
        int ocb = 16 * (2 * wv + a) + lg * 4;
#pragma unroll
        for (int e = 0; e < 4; ++e) {
            float bv = conv_b[ocb + e];
            acc[a][0][e] = bv;
            acc[a][1][e] = bv;
        }
    }

    const ushort* wr0 = wb + (size_t)(16 * (2 * wv + 0) + lr) * KTOT + lg * 8;
    const ushort* wr1 = wb + (size_t)(16 * (2 * wv + 1) + lr) * KTOT + lg * 8;
    const ushort* s0  = &S[(lr) * SST + lg * 8];
    const ushort* s1  = &S[(16 + lr) * SST + lg * 8];

    for (int ks = 0; ks < 18; ++ks) {
        int kk = ks * 32;
        short8t a0 = *(const short8t*)(wr0 + kk);
        short8t a1 = *(const short8t*)(wr1 + kk);
        short8t b0 = *(const short8t*)(s0 + kk);
        short8t b1 = *(const short8t*)(s1 + kk);
        acc[0][0] = __builtin_amdgcn_mfma_f32_16x16x32_bf16(a0, b0, acc[0][0], 0, 0, 0);
        acc[0][1] = __builtin_amdgcn_mfma_f32_16x16x32_bf16(a0, b1, acc[0][1], 0, 0, 0);
        acc[1][0] = __builtin_amdgcn_mfma_f32_16x16x32_bf16(a1, b0, acc[1][0], 0, 0, 0);
        acc[1][1] = __builtin_amdgcn_mfma_f32_16x16x32_bf16(a1, b1, acc[1][1], 0, 0, 0);
    }

    float* ob = out + ((size_t)b * OCC * HH + oi) * WW + oj0;
#pragma unroll
    for (int a = 0; a < 2; ++a) {
        int ocb = 16 * (2 * wv + a) + lg * 4;
#pragma unroll
        for (int p = 0; p < 2; ++p) {
#pragma unroll
            for (int e = 0; e < 4; ++e) {
                int oc  = ocb + e;
                int col = 16 * p + lr;
                ob[(size_t)oc * HWx + col] = acc[a][p][e];
            }
        }
    }
}

extern "C" void kernel_launch(void* const* d_in, const int* in_sizes, int n_in,
                              void* d_out, int out_size, void* d_ws, size_t ws_size,
                              hipStream_t stream) {
    const float* x      = (const float*)d_in[0];
    const float* off_w  = (const float*)d_in[1];
    const float* off_b  = (const float*)d_in[2];
    const float* conv_w = (const float*)d_in[3];
    const float* conv_b = (const float*)d_in[4];
    float* out = (float*)d_out;

    ushort* wbf   = (ushort*)d_ws;                            // 147456 B
    float*  offsT = (float*)((char*)d_ws + 147456);           // 9.44 MB
    ushort* xT    = (ushort*)((char*)d_ws + 147456 + 9437184);// 16.78 MB

    kprep<<<(OCC * KTOT) / 256, 256, 0, stream>>>(conv_w, wbf);
    ktrans<<<BB * (HWx / 256), 256, 0, stream>>>(x, xT);
    koff<<<BB * HH, 256, 0, stream>>>(x, off_w, off_b, offsT);
    kmain5<<<BB * HH * 4, 256, 0, stream>>>(xT, offsT, wbf, conv_b, out);
}

// Round 6
// 211.978 us; speedup vs baseline: 2.0904x; 1.0450x over previous
//
#include <hip/hip_runtime.h>

#define BB   8
#define CC   64
#define HH   128
#define WW   128
#define OCC  128
#define HWx  (HH*WW)
#define KTOT 576
#define SST  584    // ushort row stride: 576 + 8 (1168 B, 16B-multiple)

typedef __attribute__((ext_vector_type(8))) short short8t;
typedef __attribute__((ext_vector_type(4))) float f32x4;

static __device__ __forceinline__ ushort f2bf(float f) {
    uint u = __float_as_uint(f);
    uint r = (u + 0x7fffu + ((u >> 16) & 1u)) >> 16;   // RNE
    return (ushort)r;
}
static __device__ __forceinline__ float bf2f(ushort u) {
    return __uint_as_float(((uint)u) << 16);
}

// ---- K0: conv_w [oc][c*9+tap] fp32 -> wb [oc][tap*64+c] bf16 --------------
__global__ __launch_bounds__(256) void kprep(const float* __restrict__ w,
                                             ushort* __restrict__ wb) {
    int i = blockIdx.x * 256 + threadIdx.x;   // 73728
    int oc = i / KTOT, k = i - oc * KTOT;
    int c = k / 9, tap = k - c * 9;
    wb[oc * KTOT + tap * 64 + c] = f2bf(w[i]);
}

// ---- K0b: x NCHW fp32 -> xT NHWC bf16, direct (no LDS) --------------------
// block: 64 pixels x 64 ch; thread: 1 pixel x 16 ch. grid = BB*256.
__global__ __launch_bounds__(256) void ktrans(const float* __restrict__ x,
                                              ushort* __restrict__ xT) {
    int tid = threadIdx.x;
    int b   = blockIdx.x >> 8;
    int p   = (blockIdx.x & 255) * 64 + (tid & 63);
    int cg  = tid >> 6;                  // 0..3 -> channels cg*16..+15
    const float* xb = x + (size_t)b * CC * HWx + p;
    ushort* ob = xT + ((size_t)b * HWx + p) * 64 + cg * 16;
    short8t v0, v1;
#pragma unroll
    for (int e = 0; e < 8; ++e) v0[e] = (short)f2bf(xb[(size_t)(cg * 16 + e) * HWx]);
#pragma unroll
    for (int e = 0; e < 8; ++e) v1[e] = (short)f2bf(xb[(size_t)(cg * 16 + 8 + e) * HWx]);
    *(short8t*)ob = v0;
    *(short8t*)(ob + 8) = v1;
}

// ---- K1: offset conv (ch 0..17), fp32 exact, writes offsT[pix][18] --------
__global__ __launch_bounds__(256) void koff(const float* __restrict__ x,
                                            const float* __restrict__ off_w,
                                            const float* __restrict__ off_b,
                                            float* __restrict__ offsT) {
    __shared__ float wl[576][20];
    int tid = threadIdx.x;
    for (int idx = tid; idx < 18 * 576; idx += 256) {
        int ch = idx / 576, r = idx - ch * 576;
        wl[r][ch] = off_w[ch * 576 + r];
    }
    __syncthreads();

    int b = blockIdx.x >> 7;
    int i = blockIdx.x & 127;
    int g = tid >> 7;            // channel group: ch = g*9 + u
    int j = tid & 127;
    const float* xb = x + (size_t)b * CC * HWx;

    float acc[9];
#pragma unroll
    for (int u = 0; u < 9; ++u) acc[u] = off_b[g * 9 + u];

    for (int c = 0; c < CC; ++c) {
        const float* xc = xb + (size_t)c * HWx;
#pragma unroll
        for (int di = 0; di < 3; ++di) {
            int r = i + di - 1;
            bool rv = (r >= 0) && (r < HH);
#pragma unroll
            for (int dj = 0; dj < 3; ++dj) {
                int s = j + dj - 1;
                float xv = (rv && s >= 0 && s < WW) ? xc[r * WW + s] : 0.f;
                const float* wrow = &wl[c * 9 + di * 3 + dj][g * 9];
#pragma unroll
                for (int u = 0; u < 9; ++u)
                    acc[u] = fmaf(xv, wrow[u], acc[u]);
            }
        }
    }
    float* ob = offsT + ((size_t)(b * HWx) + i * WW + j) * 18 + g * 9;
#pragma unroll
    for (int u = 0; u < 9; ++u) ob[u] = acc[u];
}

// ---- K2: fused vector-gather + MFMA stride-3 conv -------------------------
// Block: 256 thr, 32 pixels x 128 oc. grid = 8*128*4 = 4096.
__global__ __launch_bounds__(256) void kmain6(const ushort* __restrict__ xT,
                                              const float* __restrict__ offsT,
                                              const ushort* __restrict__ wb,
                                              const float* __restrict__ conv_b,
                                              float* __restrict__ out) {
    __shared__ __align__(16) ushort S[32 * SST];   // 37376 B
    int tid = threadIdx.x;
    int bi  = blockIdx.x;
    int b   = bi >> 9;
    int rem = bi & 511;
    int oi  = rem >> 2;
    int oj0 = (rem & 3) * 32;

    const ushort* xTb  = xT + (size_t)b * HWx * 64;
    const float*  offb = offsT + (size_t)b * HWx * 18;

    // ---- phase 2 pointer setup + ks=0 weight prefetch (independent of S) --
    int wv = tid >> 6;
    int l  = tid & 63;
    int lr = l & 15;
    int lg = l >> 4;
    const ushort* wr0 = wb + (size_t)(16 * (2 * wv + 0) + lr) * KTOT + lg * 8;
    const ushort* wr1 = wb + (size_t)(16 * (2 * wv + 1) + lr) * KTOT + lg * 8;
    short8t pa0 = *(const short8t*)(wr0);
    short8t pa1 = *(const short8t*)(wr1);

    // ---- phase 1: 2304 subtasks = (pix, tap, 8-ch group), 9 per thread ----
#pragma unroll 3
    for (int it = 0; it < 9; ++it) {
        int s   = tid + it * 256;
        int pix = s / 72;
        int r   = s - pix * 72;
        int tap = r >> 3;
        int cg  = r & 7;
        int kr = tap / 3, kc = tap - kr * 3;
        int si = oi + ((kr == 0) ? -1 : 0);
        int sj = oj0 + pix + ((kc == 0) ? -1 : 0);
        ushort* Sd = &S[pix * SST + tap * 64 + cg * 8];

        if (si < 0 || sj < 0) {
            short8t z = {0, 0, 0, 0, 0, 0, 0, 0};
            *(short8t*)Sd = z;
            continue;
        }
        int n    = ((kr == 0) ? 2 : kr - 1) * 3 + ((kc == 0) ? 2 : kc - 1);
        int pidx = si * WW + sj;
        float ox = offb[pidx * 18 + n];
        float oy = offb[pidx * 18 + 9 + n];
        float px = (float)si + ox;
        float py = (float)sj + oy;
        float fx = floorf(px), fy = floorf(py);
        float pxc   = fminf(fmaxf(px, 0.f), 127.f);
        float pyc   = fminf(fmaxf(py, 0.f), 127.f);
        float qltxf = fminf(fmaxf(fx, 0.f), 127.f);
        float qltyf = fminf(fmaxf(fy, 0.f), 127.f);
        float qrbxf = fminf(fmaxf(fx + 1.f, 0.f), 127.f);
        float qrbyf = fminf(fmaxf(fy + 1.f, 0.f), 127.f);
        int qltx = (int)qltxf, qlty = (int)qltyf;
        int qrbx = (int)qrbxf, qrby = (int)qrbyf;
        float glt = (1.f + (qltxf - pxc)) * (1.f + (qltyf - pyc));
        float grb = (1.f - (qrbxf - pxc)) * (1.f - (qrbyf - pyc));
        float glb = (1.f + (qltxf - pxc)) * (1.f - (qrbyf - pyc));
        float grt = (1.f - (qrbxf - pxc)) * (1.f + (qltyf - pyc));
        int co = cg * 8;
        short8t lt = *(const short8t*)(xTb + (size_t)(qltx * WW + qlty) * 64 + co);
        short8t rb = *(const short8t*)(xTb + (size_t)(qrbx * WW + qrby) * 64 + co);
        short8t lb = *(const short8t*)(xTb + (size_t)(qltx * WW + qrby) * 64 + co);
        short8t rt = *(const short8t*)(xTb + (size_t)(qrbx * WW + qlty) * 64 + co);
        short8t o;
#pragma unroll
        for (int e = 0; e < 8; ++e) {
            float v = glt * bf2f((ushort)lt[e]) + grb * bf2f((ushort)rb[e])
                    + glb * bf2f((ushort)lb[e]) + grt * bf2f((ushort)rt[e]);
            o[e] = (short)f2bf(v);
        }
        *(short8t*)Sd = o;
    }
    __syncthreads();

    // ---- phase 2: 128oc x 32pix x 576K GEMM (16x16x32 bf16 MFMA) ----
    f32x4 acc[2][2];
#pragma unroll
    for (int a = 0; a < 2; ++a) {
        int ocb = 16 * (2 * wv + a) + lg * 4;
#pragma unroll
        for (int e = 0; e < 4; ++e) {
            float bv = conv_b[ocb + e];
            acc[a][0][e] = bv;
            acc[a][1][e] = bv;
        }
    }
    const ushort* s0 = &S[(lr) * SST + lg * 8];
    const ushort* s1 = &S[(16 + lr) * SST + lg * 8];

#pragma unroll 3
    for (int ks = 0; ks < 18; ++ks) {
        int kk = ks * 32;
        short8t a0 = (ks == 0) ? pa0 : *(const short8t*)(wr0 + kk);
        short8t a1 = (ks == 0) ? pa1 : *(const short8t*)(wr1 + kk);
        short8t b0 = *(const short8t*)(s0 + kk);
        short8t b1 = *(const short8t*)(s1 + kk);
        acc[0][0] = __builtin_amdgcn_mfma_f32_16x16x32_bf16(a0, b0, acc[0][0], 0, 0, 0);
        acc[0][1] = __builtin_amdgcn_mfma_f32_16x16x32_bf16(a0, b1, acc[0][1], 0, 0, 0);
        acc[1][0] = __builtin_amdgcn_mfma_f32_16x16x32_bf16(a1, b0, acc[1][0], 0, 0, 0);
        acc[1][1] = __builtin_amdgcn_mfma_f32_16x16x32_bf16(a1, b1, acc[1][1], 0, 0, 0);
    }

    float* ob = out + ((size_t)b * OCC * HH + oi) * WW + oj0;
#pragma unroll
    for (int a = 0; a < 2; ++a) {
        int ocb = 16 * (2 * wv + a) + lg * 4;
#pragma unroll
        for (int p = 0; p < 2; ++p) {
#pragma unroll
            for (int e = 0; e < 4; ++e) {
                int oc  = ocb + e;
                int col = 16 * p + lr;
                ob[(size_t)oc * HWx + col] = acc[a][p][e];
            }
        }
    }
}

extern "C" void kernel_launch(void* const* d_in, const int* in_sizes, int n_in,
                              void* d_out, int out_size, void* d_ws, size_t ws_size,
                              hipStream_t stream) {
    const float* x      = (const float*)d_in[0];
    const float* off_w  = (const float*)d_in[1];
    const float* off_b  = (const float*)d_in[2];
    const float* conv_w = (const float*)d_in[3];
    const float* conv_b = (const float*)d_in[4];
    float* out = (float*)d_out;

    ushort* wbf   = (ushort*)d_ws;                            // 147456 B
    float*  offsT = (float*)((char*)d_ws + 147456);           // 9.44 MB
    ushort* xT    = (ushort*)((char*)d_ws + 147456 + 9437184);// 16.78 MB

    kprep<<<(OCC * KTOT) / 256, 256, 0, stream>>>(conv_w, wbf);
    ktrans<<<BB * (HWx / 64), 256, 0, stream>>>(x, xT);
    koff<<<BB * HH, 256, 0, stream>>>(x, off_w, off_b, offsT);
    kmain6<<<BB * HH * 4, 256, 0, stream>>>(xT, offsT, wbf, conv_b, out);
}

// Round 9
// 170.611 us; speedup vs baseline: 2.5973x; 1.2425x over previous
//
#include <hip/hip_runtime.h>

#define BB   8
#define CC   64
#define HH   128
#define WW   128
#define OCC  128
#define HWx  (HH*WW)
#define KTOT 576
#define SST  584    // ushort row stride: 576 + 8 (1168 B, 16B-multiple)

typedef __attribute__((ext_vector_type(8))) short short8t;
typedef __attribute__((ext_vector_type(4))) float f32x4;

static __device__ __forceinline__ ushort f2bf(float f) {
    uint u = __float_as_uint(f);
    uint r = (u + 0x7fffu + ((u >> 16) & 1u)) >> 16;   // RNE
    return (ushort)r;
}
static __device__ __forceinline__ float bf2f(ushort u) {
    return __uint_as_float(((uint)u) << 16);
}

// ---- K0: conv_w [oc][c*9+tap] fp32 -> wb [oc][tap*64+c] bf16 (R6 verbatim) -
__global__ __launch_bounds__(256) void kprep(const float* __restrict__ w,
                                             ushort* __restrict__ wb) {
    int i = blockIdx.x * 256 + threadIdx.x;   // 73728
    int oc = i / KTOT, k = i - oc * KTOT;
    int c = k / 9, tap = k - c * 9;
    wb[oc * KTOT + tap * 64 + c] = f2bf(w[i]);
}

// ---- K0c: off_w [ch][c*9+tap] -> wT [(c*9+tap)*18 + ch] fp32 (exact copy) -
__global__ __launch_bounds__(256) void kprepw(const float* __restrict__ ow,
                                              float* __restrict__ wT) {
    int i = blockIdx.x * 256 + threadIdx.x;   // 18*576 = 10368
    if (i < 18 * KTOT) {
        int ch = i / KTOT, r = i - ch * KTOT;
        wT[r * 18 + ch] = ow[i];
    }
}

// ---- K0b: x NCHW fp32 -> xT NHWC bf16, direct (R6 verbatim) ---------------
__global__ __launch_bounds__(256) void ktrans(const float* __restrict__ x,
                                              ushort* __restrict__ xT) {
    int tid = threadIdx.x;
    int b   = blockIdx.x >> 8;
    int p   = (blockIdx.x & 255) * 64 + (tid & 63);
    int cg  = tid >> 6;                  // 0..3 -> channels cg*16..+15
    const float* xb = x + (size_t)b * CC * HWx + p;
    ushort* ob = xT + ((size_t)b * HWx + p) * 64 + cg * 16;
    short8t v0, v1;
#pragma unroll
    for (int e = 0; e < 8; ++e) v0[e] = (short)f2bf(xb[(size_t)(cg * 16 + e) * HWx]);
#pragma unroll
    for (int e = 0; e < 8; ++e) v1[e] = (short)f2bf(xb[(size_t)(cg * 16 + 8 + e) * HWx]);
    *(short8t*)ob = v0;
    *(short8t*)(ob + 8) = v1;
}

// ---- K1: offset conv (ch 0..17), fp32 exact. R6 structure, LDS-free. ------
// One block per (b,i) row; g = tid>>7 selects channel half (wave-uniform).
// Weights read from pre-transposed wT via scalar loads. grid = BB*HH.
__global__ __launch_bounds__(256) void koff5(const float* __restrict__ x,
                                             const float* __restrict__ wT,
                                             const float* __restrict__ off_b,
                                             float* __restrict__ offsT) {
    int tid = threadIdx.x;
    int b = blockIdx.x >> 7;
    int i = blockIdx.x & 127;
    int g9 = __builtin_amdgcn_readfirstlane((tid >> 7) * 9);  // wave-uniform
    int j = tid & 127;
    const float* xb = x + (size_t)b * CC * HWx;

    float acc[9];
#pragma unroll
    for (int u = 0; u < 9; ++u) acc[u] = off_b[g9 + u];

    for (int c = 0; c < CC; ++c) {
        const float* xc = xb + (size_t)c * HWx;
#pragma unroll
        for (int di = 0; di < 3; ++di) {
            int r = i + di - 1;
            bool rv = (r >= 0) && (r < HH);
#pragma unroll
            for (int dj = 0; dj < 3; ++dj) {
                int s = j + dj - 1;
                float xv = (rv && s >= 0 && s < WW) ? xc[r * WW + s] : 0.f;
                const float* wrow = &wT[(c * 9 + di * 3 + dj) * 18 + g9];
#pragma unroll
                for (int u = 0; u < 9; ++u)
                    acc[u] = fmaf(xv, wrow[u], acc[u]);
            }
        }
    }
    float* ob = offsT + ((size_t)(b * HWx) + i * WW + j) * 18 + g9;
#pragma unroll
    for (int u = 0; u < 9; ++u) ob[u] = acc[u];
}

// ---- K2: fused vector-gather + MFMA stride-3 conv (R6 verbatim except b) --
// Block: 256 thr, 32 pixels x 128 oc. grid = 4096, b = bi&7 (XCD<->batch).
__global__ __launch_bounds__(256) void kmain9(const ushort* __restrict__ xT,
                                              const float* __restrict__ offsT,
                                              const ushort* __restrict__ wb,
                                              const float* __restrict__ conv_b,
                                              float* __restrict__ out) {
    __shared__ __align__(16) ushort S[32 * SST];   // 37376 B
    int tid = threadIdx.x;
    int bi  = blockIdx.x;
    int b   = bi & 7;                  // XCD-affine batch
    int rem = bi >> 3;
    int oi  = rem >> 2;
    int oj0 = (rem & 3) * 32;

    const ushort* xTb  = xT + (size_t)b * HWx * 64;
    const float*  offb = offsT + (size_t)b * HWx * 18;

    // ---- phase 2 pointer setup + ks=0 weight prefetch (independent of S) --
    int wv = tid >> 6;
    int l  = tid & 63;
    int lr = l & 15;
    int lg = l >> 4;
    const ushort* wr0 = wb + (size_t)(16 * (2 * wv + 0) + lr) * KTOT + lg * 8;
    const ushort* wr1 = wb + (size_t)(16 * (2 * wv + 1) + lr) * KTOT + lg * 8;
    short8t pa0 = *(const short8t*)(wr0);
    short8t pa1 = *(const short8t*)(wr1);

    // ---- phase 1: 2304 subtasks = (pix, tap, 8-ch group), 9 per thread ----
#pragma unroll 3
    for (int it = 0; it < 9; ++it) {
        int s   = tid + it * 256;
        int pix = s / 72;
        int r   = s - pix * 72;
        int tap = r >> 3;
        int cg  = r & 7;
        int kr = tap / 3, kc = tap - kr * 3;
        int si = oi + ((kr == 0) ? -1 : 0);
        int sj = oj0 + pix + ((kc == 0) ? -1 : 0);
        ushort* Sd = &S[pix * SST + tap * 64 + cg * 8];

        if (si < 0 || sj < 0) {
            short8t z = {0, 0, 0, 0, 0, 0, 0, 0};
            *(short8t*)Sd = z;
            continue;
        }
        int n    = ((kr == 0) ? 2 : kr - 1) * 3 + ((kc == 0) ? 2 : kc - 1);
        int pidx = si * WW + sj;
        float ox = offb[pidx * 18 + n];
        float oy = offb[pidx * 18 + 9 + n];
        float px = (float)si + ox;
        float py = (float)sj + oy;
        float fx = floorf(px), fy = floorf(py);
        float pxc   = fminf(fmaxf(px, 0.f), 127.f);
        float pyc   = fminf(fmaxf(py, 0.f), 127.f);
        float qltxf = fminf(fmaxf(fx, 0.f), 127.f);
        float qltyf = fminf(fmaxf(fy, 0.f), 127.f);
        float qrbxf = fminf(fmaxf(fx + 1.f, 0.f), 127.f);
        float qrbyf = fminf(fmaxf(fy + 1.f, 0.f), 127.f);
        int qltx = (int)qltxf, qlty = (int)qltyf;
        int qrbx = (int)qrbxf, qrby = (int)qrbyf;
        float glt = (1.f + (qltxf - pxc)) * (1.f + (qltyf - pyc));
        float grb = (1.f - (qrbxf - pxc)) * (1.f - (qrbyf - pyc));
        float glb = (1.f + (qltxf - pxc)) * (1.f - (qrbyf - pyc));
        float grt = (1.f - (qrbxf - pxc)) * (1.f + (qltyf - pyc));
        int co = cg * 8;
        short8t lt = *(const short8t*)(xTb + (size_t)(qltx * WW + qlty) * 64 + co);
        short8t rb = *(const short8t*)(xTb + (size_t)(qrbx * WW + qrby) * 64 + co);
        short8t lb = *(const short8t*)(xTb + (size_t)(qltx * WW + qrby) * 64 + co);
        short8t rt = *(const short8t*)(xTb + (size_t)(qrbx * WW + qlty) * 64 + co);
        short8t o;
#pragma unroll
        for (int e = 0; e < 8; ++e) {
            float v = glt * bf2f((ushort)lt[e]) + grb * bf2f((ushort)rb[e])
                    + glb * bf2f((ushort)lb[e]) + grt * bf2f((ushort)rt[e]);
            o[e] = (short)f2bf(v);
        }
        *(short8t*)Sd = o;
    }
    __syncthreads();

    // ---- phase 2: 128oc x 32pix x 576K GEMM (16x16x32 bf16 MFMA) ----
    f32x4 acc[2][2];
#pragma unroll
    for (int a = 0; a < 2; ++a) {
        int ocb = 16 * (2 * wv + a) + lg * 4;
#pragma unroll
        for (int e = 0; e < 4; ++e) {
            float bv = conv_b[ocb + e];
            acc[a][0][e] = bv;
            acc[a][1][e] = bv;
        }
    }
    const ushort* s0 = &S[(lr) * SST + lg * 8];
    const ushort* s1 = &S[(16 + lr) * SST + lg * 8];

#pragma unroll 3
    for (int ks = 0; ks < 18; ++ks) {
        int kk = ks * 32;
        short8t a0 = (ks == 0) ? pa0 : *(const short8t*)(wr0 + kk);
        short8t a1 = (ks == 0) ? pa1 : *(const short8t*)(wr1 + kk);
        short8t b0 = *(const short8t*)(s0 + kk);
        short8t b1 = *(const short8t*)(s1 + kk);
        acc[0][0] = __builtin_amdgcn_mfma_f32_16x16x32_bf16(a0, b0, acc[0][0], 0, 0, 0);
        acc[0][1] = __builtin_amdgcn_mfma_f32_16x16x32_bf16(a0, b1, acc[0][1], 0, 0, 0);
        acc[1][0] = __builtin_amdgcn_mfma_f32_16x16x32_bf16(a1, b0, acc[1][0], 0, 0, 0);
        acc[1][1] = __builtin_amdgcn_mfma_f32_16x16x32_bf16(a1, b1, acc[1][1], 0, 0, 0);
    }

    float* ob = out + ((size_t)b * OCC * HH + oi) * WW + oj0;
#pragma unroll
    for (int a = 0; a < 2; ++a) {
        int ocb = 16 * (2 * wv + a) + lg * 4;
#pragma unroll
        for (int p = 0; p < 2; ++p) {
#pragma unroll
            for (int e = 0; e < 4; ++e) {
                int oc  = ocb + e;
                int col = 16 * p + lr;
                ob[(size_t)oc * HWx + col] = acc[a][p][e];
            }
        }
    }
}

extern "C" void kernel_launch(void* const* d_in, const int* in_sizes, int n_in,
                              void* d_out, int out_size, void* d_ws, size_t ws_size,
                              hipStream_t stream) {
    const float* x      = (const float*)d_in[0];
    const float* off_w  = (const float*)d_in[1];
    const float* off_b  = (const float*)d_in[2];
    const float* conv_w = (const float*)d_in[3];
    const float* conv_b = (const float*)d_in[4];
    float* out = (float*)d_out;

    ushort* wbf   = (ushort*)d_ws;                              // 147456 B
    float*  offsT = (float*)((char*)d_ws + 147456);             // 9.44 MB
    ushort* xT    = (ushort*)((char*)d_ws + 147456 + 9437184);  // 16.78 MB
    float*  wT    = (float*)((char*)d_ws + 147456 + 9437184 + 16777216); // 41.5 KB

    kprep<<<(OCC * KTOT) / 256, 256, 0, stream>>>(conv_w, wbf);
    kprepw<<<41, 256, 0, stream>>>(off_w, wT);
    ktrans<<<BB * (HWx / 64), 256, 0, stream>>>(x, xT);
    koff5<<<BB * HH, 256, 0, stream>>>(x, wT, off_b, offsT);
    kmain9<<<BB * HH * 4, 256, 0, stream>>>(xT, offsT, wbf, conv_b, out);
}